// Round 9
// baseline (100.280 us; speedup 1.0000x reference)
//
#include <hip/hip_runtime.h>
#include <hip/hip_bf16.h>

typedef __attribute__((ext_vector_type(8))) short bf16x8;
typedef __attribute__((ext_vector_type(4))) float f32x4;
typedef __attribute__((ext_vector_type(8))) unsigned short u16x8;

__device__ __forceinline__ void gload16(const void* g, void* l) {
    __builtin_amdgcn_global_load_lds((const __attribute__((address_space(1))) void*)g,
                                     (__attribute__((address_space(3))) void*)l, 16, 0, 0);
}
__device__ __forceinline__ float bf2f(unsigned short u) {
    union { unsigned i; float f; } v; v.i = ((unsigned)u) << 16; return v.f;
}
__device__ __forceinline__ unsigned short f2bf(float f) {
    __hip_bfloat16 h = __float2bfloat16(f);
    return *(unsigned short*)&h;
}

// ---------------------------------------------------------------------------
// conv_chunk: one 8-elem fp32->bf16 zero-padded conversion chunk.
// ---------------------------------------------------------------------------
__device__ __forceinline__ void conv_chunk(
    const float* __restrict__ src, int ld, int col0, int M, int K, int Kp,
    unsigned short* __restrict__ dst, int cid)
{
    const int kp8 = Kp >> 3;
    const int m = cid / kp8;
    const int kc = (cid - m * kp8) << 3;
    u16x8 v;
    if (m < M && kc + 8 <= K) {
        const float* s = src + (size_t)m * ld + col0 + kc;
        const float4 f0 = *(const float4*)s;
        const float4 f1 = *(const float4*)(s + 4);
        const float ff[8] = {f0.x, f0.y, f0.z, f0.w, f1.x, f1.y, f1.z, f1.w};
        #pragma unroll
        for (int j = 0; j < 8; ++j) v[j] = f2bf(ff[j]);
    } else {
        #pragma unroll
        for (int j = 0; j < 8; ++j) {
            float f = 0.f;
            const int k = kc + j;
            if (m < M && k < K) f = src[(size_t)m * ld + col0 + k];
            v[j] = f2bf(f);
        }
    }
    *(u16x8*)(dst + (size_t)m * Kp + kc) = v;
}

// ---------------------------------------------------------------------------
// stage_f32: reg-staged ROWSx64 fp32->bf16 tile into XOR-swizzled LDS (G1).
// ---------------------------------------------------------------------------
template<int ROWS>
__device__ __forceinline__ void stage_f32(
    const float* __restrict__ src, int ld, int row0, int rmax,
    int k0, int kmax, short* __restrict__ lds, int tid)
{
    #pragma unroll
    for (int i = 0; i < ROWS / 32; ++i) {
        const int ch = i * 256 + tid;
        const int r = ch >> 3;
        const int kc8 = (ch & 7) * 8;
        const int gr = row0 + r;
        const int gk = k0 + kc8;
        u16x8 v;
        if (gr < rmax && gk + 8 <= kmax) {
            const float* s = src + (size_t)gr * ld + gk;
            const float4 f0 = *(const float4*)s;
            const float4 f1 = *(const float4*)(s + 4);
            const float ff[8] = {f0.x, f0.y, f0.z, f0.w, f1.x, f1.y, f1.z, f1.w};
            #pragma unroll
            for (int j = 0; j < 8; ++j) v[j] = f2bf(ff[j]);
        } else if (gr < rmax && gk < kmax) {
            #pragma unroll
            for (int j = 0; j < 8; ++j) {
                float f = 0.f;
                if (gk + j < kmax) f = src[(size_t)gr * ld + gk + j];
                v[j] = f2bf(f);
            }
        } else {
            v = (u16x8){0, 0, 0, 0, 0, 0, 0, 0};
        }
        *(u16x8*)((char*)lds + r * 128 + ((kc8 * 2) ^ ((r & 7) << 4))) = v;
    }
}

// ---------------------------------------------------------------------------
// stage_gl: ROWSx64 bf16 tile -> linear LDS via global_load_lds w16,
// source byte-col XOR-pre-swizzled (rule #21 both-sides).
// ---------------------------------------------------------------------------
template<int ROWS>
__device__ __forceinline__ void stage_gl(const unsigned short* __restrict__ src,
                                         int ld, int row0, int k0,
                                         short* __restrict__ lds, int w, int l)
{
    const int sr0 = w * 8 + (l >> 3);
    const int scb = (l & 7) * 16;
    #pragma unroll
    for (int c = 0; c < ROWS / 32; ++c) {
        const int r = c * 32 + sr0;
        const int cbs = scb ^ ((r & 7) << 4);
        const char* g = (const char*)(src + (size_t)(row0 + r) * ld + k0) + cbs;
        char* dst = (char*)lds + (size_t)(c * 32 + w * 8) * 128;
        gload16(g, dst);
    }
}

// ---------------------------------------------------------------------------
// 64x64 GEMM body (relu+bias, bf16 out) — G2.
// ---------------------------------------------------------------------------
__device__ __forceinline__ void gemm64_body(
    const unsigned short* __restrict__ A, const unsigned short* __restrict__ B,
    const float* __restrict__ bias, unsigned short* __restrict__ Cout, int ldc,
    int bm, int bn, int Kp, int Mtrue,
    short* As, short* Bs, int tid)
{
    const int w = tid >> 6, l = tid & 63;
    const int wm = w >> 1, wn = w & 1;
    f32x4 acc[2][2];
    #pragma unroll
    for (int i = 0; i < 2; ++i)
        #pragma unroll
        for (int j = 0; j < 2; ++j)
            acc[i][j] = (f32x4){0.f, 0.f, 0.f, 0.f};

    for (int k0 = 0; k0 < Kp; k0 += 64) {
        stage_gl<64>(A, Kp, bm, k0, As, w, l);
        stage_gl<64>(B, Kp, bn, k0, Bs, w, l);
        asm volatile("s_waitcnt vmcnt(0)");
        __syncthreads();
        #pragma unroll
        for (int ks = 0; ks < 64; ks += 32) {
            bf16x8 a[2], b[2];
            const int kb = ks * 2 + (l >> 4) * 16;
            #pragma unroll
            for (int i = 0; i < 2; ++i) {
                const int ra = wm * 32 + i * 16 + (l & 15);
                a[i] = *(const bf16x8*)((const char*)As + ra * 128 + (kb ^ ((ra & 7) << 4)));
                const int rb = wn * 32 + i * 16 + (l & 15);
                b[i] = *(const bf16x8*)((const char*)Bs + rb * 128 + (kb ^ ((rb & 7) << 4)));
            }
            #pragma unroll
            for (int i = 0; i < 2; ++i)
                #pragma unroll
                for (int j = 0; j < 2; ++j)
                    acc[i][j] = __builtin_amdgcn_mfma_f32_16x16x32_bf16(a[i], b[j], acc[i][j], 0, 0, 0);
        }
        __syncthreads();
    }

    #pragma unroll
    for (int i = 0; i < 2; ++i) {
        #pragma unroll
        for (int j = 0; j < 2; ++j) {
            const int col = bn + wn * 32 + j * 16 + (l & 15);
            const float bv = bias[col];
            #pragma unroll
            for (int q = 0; q < 4; ++q) {
                const int row = bm + wm * 32 + i * 16 + (l >> 4) * 4 + q;
                float v = fmaxf(acc[i][j][q] + bv, 0.f);
                if (row >= Mtrue) v = 0.f;
                Cout[(size_t)row * ldc + col] = f2bf(v);
            }
        }
    }
}

// ---------------------------------------------------------------------------
// 128x128 split-K GEMM body, fp32 atomic-accumulate into dstf [Mtrue-ish][904].
// ---------------------------------------------------------------------------
__device__ __forceinline__ void gemm128_atomic(
    const unsigned short* __restrict__ A, const unsigned short* __restrict__ B,
    float* __restrict__ dstf, int by, int bx, int k_begin, int k_steps, int Mtrue,
    short* As, short* Bs, int tid)
{
    const int w = tid >> 6, l = tid & 63;
    const int wm = w >> 1, wn = w & 1;
    f32x4 acc[4][4];
    #pragma unroll
    for (int i = 0; i < 4; ++i)
        #pragma unroll
        for (int j = 0; j < 4; ++j)
            acc[i][j] = (f32x4){0.f, 0.f, 0.f, 0.f};

    for (int t = 0; t < k_steps; ++t) {
        const int k0 = k_begin + t * 64;
        stage_gl<128>(A, 4096, by * 128, k0, As, w, l);
        stage_gl<128>(B, 4096, bx * 128, k0, Bs, w, l);
        asm volatile("s_waitcnt vmcnt(0)");
        __syncthreads();
        #pragma unroll
        for (int ks = 0; ks < 64; ks += 32) {
            bf16x8 a[4], b[4];
            const int kb = ks * 2 + (l >> 4) * 16;
            #pragma unroll
            for (int i = 0; i < 4; ++i) {
                const int ra = wm * 64 + i * 16 + (l & 15);
                a[i] = *(const bf16x8*)((const char*)As + ra * 128 + (kb ^ ((ra & 7) << 4)));
                const int rb = wn * 64 + i * 16 + (l & 15);
                b[i] = *(const bf16x8*)((const char*)Bs + rb * 128 + (kb ^ ((rb & 7) << 4)));
            }
            #pragma unroll
            for (int i = 0; i < 4; ++i)
                #pragma unroll
                for (int j = 0; j < 4; ++j)
                    acc[i][j] = __builtin_amdgcn_mfma_f32_16x16x32_bf16(a[i], b[j], acc[i][j], 0, 0, 0);
        }
        __syncthreads();
    }

    #pragma unroll
    for (int i = 0; i < 4; ++i) {
        #pragma unroll
        for (int j = 0; j < 4; ++j) {
            const int col = bx * 128 + wn * 64 + j * 16 + (l & 15);
            if (col >= 900) continue;
            #pragma unroll
            for (int q = 0; q < 4; ++q) {
                const int row = by * 128 + wm * 64 + i * 16 + (l >> 4) * 4 + q;
                if (row < Mtrue)
                    unsafeAtomicAdd(&dstf[(size_t)row * 904 + col], acc[i][j][q]);
            }
        }
    }
}

// ---------------------------------------------------------------------------
// Launch 1: G1 (60 blocks) + conversions x/W2/W3x + init hx(=b3)/ha(=0).
// Block ranges: [0,60) G1; [60,1084) x; [1084,3004) W2; [3004,5052) W3x;
// [5052,5367) init.
// ---------------------------------------------------------------------------
struct L1Args {
    const float *att, *W1, *b1; unsigned short* h1;
    const float* x;  unsigned short* x_bf;
    const float* W2; unsigned short* W2_bf;
    const float* W3; unsigned short* W3x_bf;
    const float* b3; float *hx, *ha;
};

__global__ __launch_bounds__(256)
void padg1(L1Args P)
{
    __shared__ short As[64 * 64];
    __shared__ short Bs[64 * 64];
    const int gid = blockIdx.x;
    const int tid = threadIdx.x;

    if (gid < 60) {
        const int bm = (gid & 3) * 64, bn = (gid >> 2) * 64;
        const int w = tid >> 6, l = tid & 63;
        const int wm = w >> 1, wn = w & 1;

        f32x4 acc[2][2];
        #pragma unroll
        for (int i = 0; i < 2; ++i)
            #pragma unroll
            for (int j = 0; j < 2; ++j)
                acc[i][j] = (f32x4){0.f, 0.f, 0.f, 0.f};

        for (int k0 = 0; k0 < 320; k0 += 64) {
            stage_f32<64>(P.att, 312, bm, 200, k0, 312, As, tid);
            stage_f32<64>(P.W1,  312, bn, 900, k0, 312, Bs, tid);
            __syncthreads();
            #pragma unroll
            for (int ks = 0; ks < 64; ks += 32) {
                bf16x8 a[2], b[2];
                const int kb = ks * 2 + (l >> 4) * 16;
                #pragma unroll
                for (int i = 0; i < 2; ++i) {
                    const int ra = wm * 32 + i * 16 + (l & 15);
                    a[i] = *(const bf16x8*)((const char*)As + ra * 128 + (kb ^ ((ra & 7) << 4)));
                    const int rb = wn * 32 + i * 16 + (l & 15);
                    b[i] = *(const bf16x8*)((const char*)Bs + rb * 128 + (kb ^ ((rb & 7) << 4)));
                }
                #pragma unroll
                for (int i = 0; i < 2; ++i)
                    #pragma unroll
                    for (int j = 0; j < 2; ++j)
                        acc[i][j] = __builtin_amdgcn_mfma_f32_16x16x32_bf16(a[i], b[j], acc[i][j], 0, 0, 0);
            }
            __syncthreads();
        }

        #pragma unroll
        for (int i = 0; i < 2; ++i) {
            #pragma unroll
            for (int j = 0; j < 2; ++j) {
                const int col = bn + wn * 32 + j * 16 + (l & 15);
                const float bv = (col < 900) ? P.b1[col] : 0.f;
                #pragma unroll
                for (int q = 0; q < 4; ++q) {
                    const int row = bm + wm * 32 + i * 16 + (l >> 4) * 4 + q;
                    float v = fmaxf(acc[i][j][q] + bv, 0.f);
                    if (row >= 200) v = 0.f;
                    P.h1[(size_t)row * 960 + col] = f2bf(v);
                }
            }
        }
        return;
    }

    if (gid < 1084) {          // x: [512][4096] -> bf16, 262144 chunks
        conv_chunk(P.x, 4096, 0, 512, 4096, 4096, P.x_bf, (gid - 60) * 256 + tid);
        return;
    }
    if (gid < 3004) {          // W2: [4096][900] -> bf16 [4096][960], 491520 chunks
        conv_chunk(P.W2, 900, 0, 4096, 900, 960, P.W2_bf, (gid - 1084) * 256 + tid);
        return;
    }
    if (gid < 5052) {          // W3x: [900][:4096] -> bf16 [1024][4096], 524288 chunks
        conv_chunk(P.W3, 8192, 0, 900, 4096, 4096, P.W3x_bf, (gid - 3004) * 256 + tid);
        return;
    }
    // init: hx [512][904] = b3 (57856 chunks), ha [200][904] = 0 (22600 chunks)
    int idx = (gid - 5052) * 256 + tid;
    if (idx < 57856) {
        const int m = idx / 113;
        const int c = idx - m * 113;
        const int k = c * 8;
        float f[8];
        #pragma unroll
        for (int j = 0; j < 8; ++j) f[j] = (k + j < 900) ? P.b3[k + j] : 0.f;
        float* d = P.hx + (size_t)m * 904 + k;
        *(float4*)d       = (float4){f[0], f[1], f[2], f[3]};
        *(float4*)(d + 4) = (float4){f[4], f[5], f[6], f[7]};
    } else {
        idx -= 57856;
        if (idx >= 22600) return;
        const int m = idx / 113;
        const int c = idx - m * 113;
        float* d = P.ha + (size_t)m * 904 + c * 8;
        *(float4*)d       = (float4){0.f, 0.f, 0.f, 0.f};
        *(float4*)(d + 4) = (float4){0.f, 0.f, 0.f, 0.f};
    }
}

// ---------------------------------------------------------------------------
// Launch 2: G2 (256) + G3 split-16 atomic (512) + W3a conversion (2048).
// ---------------------------------------------------------------------------
struct L2Args {
    const unsigned short *h1, *W2b; const float* b2; unsigned short* attf;
    const unsigned short *xb, *W3xb; float* hx;
    const float* W3; unsigned short* W3a_bf;
};

__global__ __launch_bounds__(256)
void g2g3w(L2Args a)
{
    __shared__ short As[128 * 64];
    __shared__ short Bs[128 * 64];
    const int gid = blockIdx.x;
    const int tid = threadIdx.x;

    if (gid < 256) {
        const int bm = (gid >> 6) * 64, bn = (gid & 63) * 64;
        gemm64_body(a.h1, a.W2b, a.b2, a.attf, 4096, bm, bn, 960, 200, As, Bs, tid);
    } else if (gid < 768) {
        const int g = gid - 256;
        const int z = g >> 5, by = (g >> 3) & 3, bx = g & 7;
        gemm128_atomic(a.xb, a.W3xb, a.hx, by, bx, z * 256, 4, 512, As, Bs, tid);
    } else {
        // W3a: [900][4096:8192] -> bf16 [1024][4096], 524288 chunks
        conv_chunk(a.W3, 8192, 4096, 900, 4096, 4096, a.W3a_bf, (gid - 768) * 256 + tid);
    }
}

// ---------------------------------------------------------------------------
// Launch 3: G4 split-16 atomic (256 blocks); block 0 thread 0 zeroes out.
// ---------------------------------------------------------------------------
struct L3Args {
    const unsigned short *attf, *W3ab; float* ha; float* out;
};

__global__ __launch_bounds__(256)
void g4z(L3Args a)
{
    __shared__ short As[128 * 64];
    __shared__ short Bs[128 * 64];
    const int gid = blockIdx.x;
    const int tid = threadIdx.x;
    if (gid == 0 && tid == 0) a.out[0] = 0.f;
    const int z = gid >> 4, by = (gid >> 3) & 1, bx = gid & 7;
    gemm128_atomic(a.attf, a.W3ab, a.ha, by, bx, z * 256, 4, 200, As, Bs, tid);
}

// ---------------------------------------------------------------------------
// Launch 4: score/loss. Stages fp32 hx/ha -> bf16 LDS; atomicAdd(out, ...)
// block = 512 thr = 4 hs x 8 si x 16 ni; grid = (4 nt, 16 st, 4 b)
// ---------------------------------------------------------------------------
__global__ __launch_bounds__(512)
void score_loss(const float* __restrict__ hx,    // [512][904] fp32 (b3 folded)
                const float* __restrict__ ha,    // [200][904] fp32
                const float* __restrict__ W4,
                const float* __restrict__ b4,
                const int* __restrict__ xl,
                const int* __restrict__ al,
                float* __restrict__ out)
{
    __shared__ __align__(16) unsigned short hxs[8 * 904];
    __shared__ __align__(16) unsigned short has[16 * 904];
    __shared__ __align__(16) float w4s[904];
    __shared__ float zpart[4][8][16];
    __shared__ float red[2];

    const int tid = threadIdx.x;
    const int nt = blockIdx.x, st = blockIdx.y, b = blockIdx.z;
    const int row0 = b * 128 + st * 8;

    for (int t = tid; t < 24 * 113; t += 512) {
        float f[8] = {0.f, 0.f, 0.f, 0.f, 0.f, 0.f, 0.f, 0.f};
        unsigned short* dst;
        if (t < 8 * 113) {
            const int r = t / 113, c = t - r * 113;
            const float* p = hx + (size_t)(row0 + r) * 904 + c * 8;
            const float4 a0 = *(const float4*)p;
            const float4 a1 = *(const float4*)(p + 4);
            f[0] = a0.x; f[1] = a0.y; f[2] = a0.z; f[3] = a0.w;
            f[4] = a1.x; f[5] = a1.y; f[6] = a1.z; f[7] = a1.w;
            dst = hxs + r * 904 + c * 8;
        } else {
            const int t2 = t - 8 * 113;
            const int r = t2 / 113, c = t2 - r * 113;
            const int n = nt * 16 + r;
            if (n < 50) {
                const float* p = ha + (size_t)(b * 50 + n) * 904 + c * 8;
                const float4 a0 = *(const float4*)p;
                const float4 a1 = *(const float4*)(p + 4);
                f[0] = a0.x; f[1] = a0.y; f[2] = a0.z; f[3] = a0.w;
                f[4] = a1.x; f[5] = a1.y; f[6] = a1.z; f[7] = a1.w;
            }
            dst = has + r * 904 + c * 8;
        }
        u16x8 v;
        #pragma unroll
        for (int j = 0; j < 8; ++j) v[j] = f2bf(f[j]);
        *(u16x8*)dst = v;
    }
    for (int t = tid; t < 226; t += 512) {
        float4 v = {0.f, 0.f, 0.f, 0.f};
        if (t < 225) v = *(const float4*)(W4 + t * 4);
        *(float4*)(w4s + t * 4) = v;
    }
    __syncthreads();

    const int hs = tid >> 7;
    const int si = (tid >> 4) & 7;
    const int ni = tid & 15;

    float acc = 0.f;
    const unsigned short* hrow = hxs + si * 904;
    const unsigned short* arow = has + ni * 904;
    for (int c = hs; c < 113; c += 4) {
        const u16x8 hv = *(const u16x8*)(hrow + c * 8);
        const u16x8 av = *(const u16x8*)(arow + c * 8);
        const float4 w0 = *(const float4*)(w4s + c * 8);
        const float4 w1 = *(const float4*)(w4s + c * 8 + 4);
        const float ww[8] = {w0.x, w0.y, w0.z, w0.w, w1.x, w1.y, w1.z, w1.w};
        #pragma unroll
        for (int j = 0; j < 8; ++j) {
            const float u = bf2f((unsigned short)hv[j]) + bf2f((unsigned short)av[j]);
            acc = fmaf(fmaxf(u, 0.f), ww[j], acc);
        }
    }
    zpart[hs][si][ni] = acc;
    __syncthreads();

    float dd = 0.f;
    if (tid < 128) {
        const int esi = tid >> 4, eni = tid & 15;
        const int n = nt * 16 + eni;
        const float z = zpart[0][esi][eni] + zpart[1][esi][eni]
                      + zpart[2][esi][eni] + zpart[3][esi][eni] + b4[0];
        const float sc = 1.f / (1.f + __expf(-z));
        if (n < 50) {
            const float lab = (xl[row0 + esi] == al[b * 50 + n]) ? 1.f : 0.f;
            const float d = lab - sc;
            dd = d * d;
        }
        #pragma unroll
        for (int off = 32; off > 0; off >>= 1)
            dd += __shfl_down(dd, off);
        if ((tid & 63) == 0) red[tid >> 6] = dd;
    }
    __syncthreads();
    if (tid == 0)
        atomicAdd(out, (red[0] + red[1]) * (1.f / 512.f));
}

extern "C" void kernel_launch(void* const* d_in, const int* in_sizes, int n_in,
                              void* d_out, int out_size, void* d_ws, size_t ws_size,
                              hipStream_t stream)
{
    const float* x   = (const float*)d_in[0];
    const int*   xl  = (const int*)  d_in[1];
    const float* att = (const float*)d_in[2];
    const int*   al  = (const int*)  d_in[3];
    const float* W1  = (const float*)d_in[4];
    const float* b1  = (const float*)d_in[5];
    const float* W2  = (const float*)d_in[6];
    const float* b2  = (const float*)d_in[7];
    const float* W3  = (const float*)d_in[8];
    const float* b3  = (const float*)d_in[9];
    const float* W4  = (const float*)d_in[10];
    const float* b4  = (const float*)d_in[11];
    float* out = (float*)d_out;

    const int MS = 512, C = 4096, Hp = 960, MNp = 256, W3p = 1024;

    char* base = (char*)d_ws;
    size_t off = 0;
    auto alloc = [&](size_t bytes) { void* r = base + off; off = (off + bytes + 255) & ~(size_t)255; return r; };
    unsigned short* x_bf   = (unsigned short*)alloc((size_t)MS * C * 2);
    unsigned short* W2_bf  = (unsigned short*)alloc((size_t)C * Hp * 2);
    unsigned short* W3x_bf = (unsigned short*)alloc((size_t)W3p * C * 2);
    unsigned short* W3a_bf = (unsigned short*)alloc((size_t)W3p * C * 2);
    unsigned short* h1_bf  = (unsigned short*)alloc((size_t)MNp * Hp * 2);
    unsigned short* attf_bf= (unsigned short*)alloc((size_t)MNp * C * 2);
    float* hx = (float*)alloc((size_t)512 * 904 * 4);
    float* ha = (float*)alloc((size_t)200 * 904 * 4);

    const dim3 blk(256);

    // ---- launch 1: G1 + conversions (x, W2, W3x) + init hx/ha ----
    L1Args P{att, W1, b1, h1_bf, x, x_bf, W2, W2_bf, W3, W3x_bf, b3, hx, ha};
    padg1<<<dim3(5367), blk, 0, stream>>>(P);

    // ---- launch 2: G2 + G3 (split-16, atomic into hx) + W3a conversion ----
    L2Args A2{h1_bf, W2_bf, b2, attf_bf, x_bf, W3x_bf, hx, W3, W3a_bf};
    g2g3w<<<dim3(2816), blk, 0, stream>>>(A2);

    // ---- launch 3: G4 (split-16, atomic into ha) + zero out ----
    L3Args A3{attf_bf, W3a_bf, ha, out};
    g4z<<<dim3(256), blk, 0, stream>>>(A3);

    // ---- launch 4: score + loss (atomic into out) ----
    score_loss<<<dim3(4, 16, 4), dim3(512), 0, stream>>>(hx, ha, W4, b4, xl, al, out);
}